// Round 2
// baseline (352.602 us; speedup 1.0000x reference)
//
#include <hip/hip_runtime.h>

typedef __attribute__((ext_vector_type(8))) short bf16x8;
typedef __attribute__((ext_vector_type(4))) float f32x4;
typedef unsigned short u16;

#define NN 8192
#define FD 256

__device__ __forceinline__ u16 f2bf(float f) {
  union { float f; unsigned u; } v; v.f = f;
  unsigned r = v.u + 0x7FFF + ((v.u >> 16) & 1);
  return (u16)(r >> 16);
}

// ---- K1: Wh = h @ W -> whT[c][r] (bf16), fused src/dst partial dot + atomicAdd ----
__global__ __launch_bounds__(256) void k_wh(const float* __restrict__ h,
                                            const float* __restrict__ W,
                                            const float* __restrict__ a,
                                            u16* __restrict__ whT,
                                            float* __restrict__ src,
                                            float* __restrict__ dst) {
  int tid = threadIdx.x;
  int lane = tid & 63;
  int wv = tid >> 6;
  int r0 = blockIdx.x * 64 + (wv >> 1) * 32;
  int c0 = blockIdx.y * 64 + (wv & 1) * 32;
  int lr = lane & 15;
  int q = lane >> 4;

  f32x4 acc[2][2] = {};
  for (int kk = 0; kk < FD; kk += 32) {
    int kb = kk + q * 8;
    bf16x8 av[2], bv[2];
#pragma unroll
    for (int m = 0; m < 2; m++) {
      const float* p = h + (size_t)(r0 + m * 16 + lr) * FD + kb;
      f32x4 x0 = *(const f32x4*)p;
      f32x4 x1 = *(const f32x4*)(p + 4);
      bf16x8 t;
      t[0] = (short)f2bf(x0[0]); t[1] = (short)f2bf(x0[1]);
      t[2] = (short)f2bf(x0[2]); t[3] = (short)f2bf(x0[3]);
      t[4] = (short)f2bf(x1[0]); t[5] = (short)f2bf(x1[1]);
      t[6] = (short)f2bf(x1[2]); t[7] = (short)f2bf(x1[3]);
      av[m] = t;
    }
#pragma unroll
    for (int n = 0; n < 2; n++) {
      int col = c0 + n * 16 + lr;
      const float* p = W + (size_t)kb * FD + col;
      bf16x8 t;
#pragma unroll
      for (int e = 0; e < 8; e++) t[e] = (short)f2bf(p[(size_t)e * FD]);
      bv[n] = t;
    }
#pragma unroll
    for (int m = 0; m < 2; m++)
#pragma unroll
      for (int n = 0; n < 2; n++)
        acc[m][n] = __builtin_amdgcn_mfma_f32_16x16x32_bf16(av[m], bv[n], acc[m][n], 0, 0, 0);
  }
#pragma unroll
  for (int m = 0; m < 2; m++)
#pragma unroll
    for (int n = 0; n < 2; n++) {
      int gc = c0 + n * 16 + lr;
      int gr = r0 + m * 16 + q * 4;
      ushort4 st;
      st.x = f2bf(acc[m][n][0]);
      st.y = f2bf(acc[m][n][1]);
      st.z = f2bf(acc[m][n][2]);
      st.w = f2bf(acc[m][n][3]);
      *(ushort4*)(whT + (size_t)gc * NN + gr) = st;
    }
  // fused: src_i += Wh[i][c0..c0+32) . a[:F] slice ; dst_i += . a[F:] slice
  float aA0 = a[c0 + lr], aA1 = a[c0 + 16 + lr];
  float aB0 = a[256 + c0 + lr], aB1 = a[256 + c0 + 16 + lr];
#pragma unroll
  for (int m = 0; m < 2; m++)
#pragma unroll
    for (int j = 0; j < 4; j++) {
      float s1 = acc[m][0][j] * aA0 + acc[m][1][j] * aA1;
      float s2 = acc[m][0][j] * aB0 + acc[m][1][j] * aB1;
#pragma unroll
      for (int sh = 1; sh < 16; sh <<= 1) {
        s1 += __shfl_xor(s1, sh);
        s2 += __shfl_xor(s2, sh);
      }
      if (lr == 0) {
        int row = r0 + m * 16 + q * 4 + j;
        atomicAdd(&src[row], s1);
        atomicAdd(&dst[row], s2);
      }
    }
}

// ---- K2: bf16 casts of h, w_ih, w_hh ----
__global__ __launch_bounds__(256) void k_cast(const float* __restrict__ h,
                                              const float* __restrict__ wih,
                                              const float* __restrict__ whh,
                                              u16* __restrict__ hb,
                                              u16* __restrict__ wihb,
                                              u16* __restrict__ whhb) {
  int g = blockIdx.x * 256 + threadIdx.x;
  const int hG = NN * FD / 4;
  const int wG = 768 * FD / 4;
  const float* sp;
  u16* dp;
  int off;
  if (g < hG) { sp = h; dp = hb; off = g; }
  else if (g < hG + wG) { sp = wih; dp = wihb; off = g - hG; }
  else { sp = whh; dp = whhb; off = g - hG - wG; }
  f32x4 x = *(const f32x4*)(sp + (size_t)off * 4);
  ushort4 y;
  y.x = f2bf(x[0]); y.y = f2bf(x[1]); y.z = f2bf(x[2]); y.w = f2bf(x[3]);
  *(ushort4*)(dp + (size_t)off * 4) = y;
}

// ---- K3: barrier-free fused masked-softmax attention + PV ----
// 512 blocks x 256 thr (4 waves). Block b: rows [b*16, b*16+16). Wave w: j in
// [w*2048, (w+1)*2048). P computed straight into A-fragment registers
// (row=lane&15, k=(lane>>4)*8+e). acc[16] f32x4 = 16 rows x 256 cols per wave.
// One LDS tree-reduce at the end combines the 4 j-quarters.
__global__ __launch_bounds__(256, 2) void k_att(const float* __restrict__ adj,
                                                const u16* __restrict__ whT,
                                                const float* __restrict__ src,
                                                const float* __restrict__ dst,
                                                u16* __restrict__ hpb) {
  __shared__ f32x4 red[2][16][64];   // 32 KB
  __shared__ float lred[4][16];
  int tid = threadIdx.x;
  int lane = tid & 63;
  int w = tid >> 6;
  int lr = lane & 15;
  int q = lane >> 4;
  int i0 = blockIdx.x * 16;

  const float* adjP = adj + (size_t)(i0 + lr) * NN + w * 2048 + q * 8;
  const float* dstP = dst + w * 2048 + q * 8;
  const u16* wp = whT + (size_t)lr * NN + w * 2048 + q * 8;
  float srcv = src[i0 + lr];

  f32x4 acc[16] = {};
  float lsum = 0.f;

  f32x4 ca0 = *(const f32x4*)(adjP);
  f32x4 ca1 = *(const f32x4*)(adjP + 4);
  f32x4 cd0 = *(const f32x4*)(dstP);
  f32x4 cd1 = *(const f32x4*)(dstP + 4);

#pragma unroll 2
  for (int t = 0; t < 64; t++) {
    float p[8];
#pragma unroll
    for (int e = 0; e < 4; e++) {
      float x = srcv + cd0[e];
      x = fmaxf(x, 0.2f * x);
      p[e] = ca0[e] * __expf(x);
    }
#pragma unroll
    for (int e = 0; e < 4; e++) {
      float x = srcv + cd1[e];
      x = fmaxf(x, 0.2f * x);
      p[4 + e] = ca1[e] * __expf(x);
    }
    if (t < 63) {  // prefetch next iter's adj/dst
      ca0 = *(const f32x4*)(adjP + (t + 1) * 32);
      ca1 = *(const f32x4*)(adjP + (t + 1) * 32 + 4);
      cd0 = *(const f32x4*)(dstP + (t + 1) * 32);
      cd1 = *(const f32x4*)(dstP + (t + 1) * 32 + 4);
    }
    lsum += ((p[0] + p[1]) + (p[2] + p[3])) + ((p[4] + p[5]) + (p[6] + p[7]));
    bf16x8 A;
#pragma unroll
    for (int e = 0; e < 8; e++) A[e] = (short)f2bf(p[e]);
    const u16* wq = wp + t * 32;
#pragma unroll
    for (int cf = 0; cf < 16; cf++) {
      bf16x8 B = *(const bf16x8*)(wq + (size_t)cf * 16 * NN);
      acc[cf] = __builtin_amdgcn_mfma_f32_16x16x32_bf16(A, B, acc[cf], 0, 0, 0);
    }
  }

  // reduce lsum over q-groups -> lanes with same lr hold this wave's row sum
  lsum += __shfl_xor(lsum, 16);
  lsum += __shfl_xor(lsum, 32);
  if (lane < 16) lred[w][lane] = lsum;

  // acc tree-reduce across the 4 waves
  if (w == 1) {
#pragma unroll
    for (int cf = 0; cf < 16; cf++) red[0][cf][lane] = acc[cf];
  }
  if (w == 3) {
#pragma unroll
    for (int cf = 0; cf < 16; cf++) red[1][cf][lane] = acc[cf];
  }
  __syncthreads();
  if (w == 0) {
#pragma unroll
    for (int cf = 0; cf < 16; cf++) acc[cf] += red[0][cf][lane];
  }
  if (w == 2) {
#pragma unroll
    for (int cf = 0; cf < 16; cf++) acc[cf] += red[1][cf][lane];
  }
  __syncthreads();
  if (w == 2) {
#pragma unroll
    for (int cf = 0; cf < 16; cf++) red[0][cf][lane] = acc[cf];
  }
  __syncthreads();
  if (w == 0) {
    float inv[4];
#pragma unroll
    for (int jj = 0; jj < 4; jj++) {
      int row = q * 4 + jj;
      inv[jj] = 1.0f / (((lred[0][row] + lred[1][row]) + (lred[2][row] + lred[3][row])));
    }
#pragma unroll
    for (int cf = 0; cf < 16; cf++) {
      f32x4 v = acc[cf] + red[0][cf][lane];
#pragma unroll
      for (int jj = 0; jj < 4; jj++) {
        int row = i0 + q * 4 + jj;
        hpb[(size_t)row * FD + cf * 16 + lr] = f2bf(v[jj] * inv[jj]);
      }
    }
  }
}

// ---- K4: fused GRUCell ----
__global__ __launch_bounds__(256) void k_gru(const u16* __restrict__ hpb,
                                             const u16* __restrict__ hb,
                                             const u16* __restrict__ wihb,
                                             const u16* __restrict__ whhb,
                                             const float* __restrict__ bih,
                                             const float* __restrict__ bhh,
                                             const float* __restrict__ h,
                                             float* __restrict__ out) {
  int tid = threadIdx.x;
  int lane = tid & 63;
  int wv = tid >> 6;
  int i0 = blockIdx.x * 32;
  int lr = lane & 15;
  int q = lane >> 4;
  int c = blockIdx.y * 64 + wv * 16 + lr;
  f32x4 gi[3][2] = {};
  f32x4 gh[3][2] = {};
  for (int kk = 0; kk < FD; kk += 32) {
    int kb = kk + q * 8;
    bf16x8 ap[2], ah[2], bi[3], bh[3];
#pragma unroll
    for (int m = 0; m < 2; m++) {
      ap[m] = *(const bf16x8*)(hpb + (size_t)(i0 + m * 16 + lr) * FD + kb);
      ah[m] = *(const bf16x8*)(hb + (size_t)(i0 + m * 16 + lr) * FD + kb);
    }
#pragma unroll
    for (int g = 0; g < 3; g++) {
      bi[g] = *(const bf16x8*)(wihb + (size_t)(g * 256 + c) * FD + kb);
      bh[g] = *(const bf16x8*)(whhb + (size_t)(g * 256 + c) * FD + kb);
    }
#pragma unroll
    for (int g = 0; g < 3; g++)
#pragma unroll
      for (int m = 0; m < 2; m++) {
        gi[g][m] = __builtin_amdgcn_mfma_f32_16x16x32_bf16(ap[m], bi[g], gi[g][m], 0, 0, 0);
        gh[g][m] = __builtin_amdgcn_mfma_f32_16x16x32_bf16(ah[m], bh[g], gh[g][m], 0, 0, 0);
      }
  }
  float bir = bih[c], biz = bih[256 + c], bin = bih[512 + c];
  float bhr = bhh[c], bhz = bhh[256 + c], bhn = bhh[512 + c];
#pragma unroll
  for (int m = 0; m < 2; m++)
#pragma unroll
    for (int j = 0; j < 4; j++) {
      int row = i0 + m * 16 + q * 4 + j;
      float rv = gi[0][m][j] + bir + gh[0][m][j] + bhr;
      float zv = gi[1][m][j] + biz + gh[1][m][j] + bhz;
      float r = 1.f / (1.f + __expf(-rv));
      float z = 1.f / (1.f + __expf(-zv));
      float nx = gi[2][m][j] + bin + r * (gh[2][m][j] + bhn);
      float n = 1.f - 2.f / (__expf(2.f * nx) + 1.f);
      float hv = h[(size_t)row * FD + c];
      out[(size_t)row * FD + c] = (1.f - z) * n + z * hv;
    }
}

extern "C" void kernel_launch(void* const* d_in, const int* in_sizes, int n_in,
                              void* d_out, int out_size, void* d_ws, size_t ws_size,
                              hipStream_t stream) {
  const float* h   = (const float*)d_in[0];
  const float* adj = (const float*)d_in[1];
  const float* W   = (const float*)d_in[2];
  const float* a   = (const float*)d_in[3];
  const float* wih = (const float*)d_in[4];
  const float* whh = (const float*)d_in[5];
  const float* bih = (const float*)d_in[6];
  const float* bhh = (const float*)d_in[7];
  float* out = (float*)d_out;

  char* ws = (char*)d_ws;
  u16* whT  = (u16*)(ws);                 // 4 MB   Wh transposed (bf16)
  u16* hpb  = (u16*)(ws + 4194304);       // 4 MB   h_prime (bf16)
  u16* hb   = (u16*)(ws + 8388608);       // 4 MB   h (bf16)
  u16* wihb = (u16*)(ws + 12582912);      // 384 KB
  u16* whhb = (u16*)(ws + 12976128);      // 384 KB
  float* srcv = (float*)(ws + 13369344);  // 32 KB
  float* dstv = (float*)(ws + 13402112);  // 32 KB

  hipMemsetAsync(ws + 13369344, 0, 65536, stream);  // zero src/dst accumulators
  k_wh<<<dim3(128, 4), 256, 0, stream>>>(h, W, a, whT, srcv, dstv);
  k_cast<<<2432, 256, 0, stream>>>(h, wih, whh, hb, wihb, whhb);
  k_att<<<512, 256, 0, stream>>>(adj, whT, srcv, dstv, hpb);
  k_gru<<<dim3(256, 4), 256, 0, stream>>>(hpb, hb, wihb, whhb, bih, bhh, h, out);
}

// Round 3
// 235.983 us; speedup vs baseline: 1.4942x; 1.4942x over previous
//
#include <hip/hip_runtime.h>

typedef __attribute__((ext_vector_type(8))) short bf16x8;
typedef __attribute__((ext_vector_type(4))) float f32x4;
typedef unsigned short u16;

#define NN 8192
#define FD 256

__device__ __forceinline__ u16 f2bf(float f) {
  union { float f; unsigned u; } v; v.f = f;
  unsigned r = v.u + 0x7FFF + ((v.u >> 16) & 1);
  return (u16)(r >> 16);
}

// ---- K1: Wh = h @ W -> whT[c][r] (bf16), fused src/dst partial dot + atomicAdd ----
__global__ __launch_bounds__(256) void k_wh(const float* __restrict__ h,
                                            const float* __restrict__ W,
                                            const float* __restrict__ a,
                                            u16* __restrict__ whT,
                                            float* __restrict__ src,
                                            float* __restrict__ dst) {
  int tid = threadIdx.x;
  int lane = tid & 63;
  int wv = tid >> 6;
  int r0 = blockIdx.x * 64 + (wv >> 1) * 32;
  int c0 = blockIdx.y * 64 + (wv & 1) * 32;
  int lr = lane & 15;
  int q = lane >> 4;

  f32x4 acc[2][2] = {};
  for (int kk = 0; kk < FD; kk += 32) {
    int kb = kk + q * 8;
    bf16x8 av[2], bv[2];
#pragma unroll
    for (int m = 0; m < 2; m++) {
      const float* p = h + (size_t)(r0 + m * 16 + lr) * FD + kb;
      f32x4 x0 = *(const f32x4*)p;
      f32x4 x1 = *(const f32x4*)(p + 4);
      bf16x8 t;
      t[0] = (short)f2bf(x0[0]); t[1] = (short)f2bf(x0[1]);
      t[2] = (short)f2bf(x0[2]); t[3] = (short)f2bf(x0[3]);
      t[4] = (short)f2bf(x1[0]); t[5] = (short)f2bf(x1[1]);
      t[6] = (short)f2bf(x1[2]); t[7] = (short)f2bf(x1[3]);
      av[m] = t;
    }
#pragma unroll
    for (int n = 0; n < 2; n++) {
      int col = c0 + n * 16 + lr;
      const float* p = W + (size_t)kb * FD + col;
      bf16x8 t;
#pragma unroll
      for (int e = 0; e < 8; e++) t[e] = (short)f2bf(p[(size_t)e * FD]);
      bv[n] = t;
    }
#pragma unroll
    for (int m = 0; m < 2; m++)
#pragma unroll
      for (int n = 0; n < 2; n++)
        acc[m][n] = __builtin_amdgcn_mfma_f32_16x16x32_bf16(av[m], bv[n], acc[m][n], 0, 0, 0);
  }
#pragma unroll
  for (int m = 0; m < 2; m++)
#pragma unroll
    for (int n = 0; n < 2; n++) {
      int gc = c0 + n * 16 + lr;
      int gr = r0 + m * 16 + q * 4;
      ushort4 st;
      st.x = f2bf(acc[m][n][0]);
      st.y = f2bf(acc[m][n][1]);
      st.z = f2bf(acc[m][n][2]);
      st.w = f2bf(acc[m][n][3]);
      *(ushort4*)(whT + (size_t)gc * NN + gr) = st;
    }
  float aA0 = a[c0 + lr], aA1 = a[c0 + 16 + lr];
  float aB0 = a[256 + c0 + lr], aB1 = a[256 + c0 + 16 + lr];
#pragma unroll
  for (int m = 0; m < 2; m++)
#pragma unroll
    for (int j = 0; j < 4; j++) {
      float s1 = acc[m][0][j] * aA0 + acc[m][1][j] * aA1;
      float s2 = acc[m][0][j] * aB0 + acc[m][1][j] * aB1;
#pragma unroll
      for (int sh = 1; sh < 16; sh <<= 1) {
        s1 += __shfl_xor(s1, sh);
        s2 += __shfl_xor(s2, sh);
      }
      if (lr == 0) {
        int row = r0 + m * 16 + q * 4 + j;
        atomicAdd(&src[row], s1);
        atomicAdd(&dst[row], s2);
      }
    }
}

// ---- K2: bf16 casts of h, w_ih, w_hh ----
__global__ __launch_bounds__(256) void k_cast(const float* __restrict__ h,
                                              const float* __restrict__ wih,
                                              const float* __restrict__ whh,
                                              u16* __restrict__ hb,
                                              u16* __restrict__ wihb,
                                              u16* __restrict__ whhb) {
  int g = blockIdx.x * 256 + threadIdx.x;
  const int hG = NN * FD / 4;
  const int wG = 768 * FD / 4;
  const float* sp;
  u16* dp;
  int off;
  if (g < hG) { sp = h; dp = hb; off = g; }
  else if (g < hG + wG) { sp = wih; dp = wihb; off = g - hG; }
  else { sp = whh; dp = whhb; off = g - hG - wG; }
  f32x4 x = *(const f32x4*)(sp + (size_t)off * 4);
  ushort4 y;
  y.x = f2bf(x[0]); y.y = f2bf(x[1]); y.z = f2bf(x[2]); y.w = f2bf(x[3]);
  *(ushort4*)(dp + (size_t)off * 4) = y;
}

// ---- K3: fused masked-softmax attention + PV, operand-swapped ----
// 256 blocks x 512 thr. Block: rows [b*32, b*32+32), full j sweep (128 steps of 64).
// Computes h'^T tile via mfma(A=whT frag (c x j), B=P^T frag (j x i)).
// P staged in LDS in MFMA-unit order -> conflict-free ds_read_b128.
// Triple-buffered P, one lgkmcnt-only barrier per step (adj/whT vmcnt queue
// survives barriers -> HBM stream stays saturated).
__global__ __launch_bounds__(512, 2) void k_att(const float* __restrict__ adj,
                                                const u16* __restrict__ whT,
                                                const float* __restrict__ src,
                                                const float* __restrict__ dst,
                                                u16* __restrict__ hpb) {
  __shared__ u16 pbuf[3][2048];     // 3 x 4 KB : P tiles (32 x 64 bf16), unit-order
  __shared__ float dst_lds[8448];   // 33 KB: dst[8192] f32; reused as out staging
  __shared__ float l_lds[32];

  const int tid = threadIdx.x;
  const int lane = tid & 63;
  const int w = tid >> 6;
  const int lr = lane & 15;
  const int q = lane >> 4;
  const int i0 = blockIdx.x * 32;

  // P-compute mapping: thread -> row pi (0..31), 4 cols at j4
  const int pi = tid >> 4;
  const int j4 = (tid & 15) * 4;
  // pbuf write slot (u16 index): blocks of 512 u16 per (kh,n), unit = q*16+i15
  const int oW = j4 >> 3;
  const int pwoff = ((oW >> 2) * 2 + (pi >> 4)) * 512 + ((oW & 3) * 16 + (pi & 15)) * 8 + ((j4 >> 2) & 1) * 4;

  const float* adjT = adj + (size_t)(i0 + pi) * NN + j4;
  const float srcv = src[i0 + pi];
  float lsum = 0.f;

  // fill dst_lds
#pragma unroll
  for (int k = 0; k < 4; k++) {
    f32x4 v = *(const f32x4*)(dst + tid * 16 + k * 4);
    *(f32x4*)&dst_lds[tid * 16 + k * 4] = v;
  }
  __syncthreads();

  f32x4 acc[2][2] = {};
  bf16x8 A0[2][2], A1[2][2];
  f32x4 R0, R1;

#define LBAR asm volatile("s_waitcnt lgkmcnt(0)\n\ts_barrier" ::: "memory")
#define RLOAD(S, R) R = *(const f32x4*)(adjT + (size_t)(S) * 64);
#define ALOAD(S, A)                                                          \
  {                                                                          \
    _Pragma("unroll") for (int m = 0; m < 2; m++)                            \
    _Pragma("unroll") for (int kh = 0; kh < 2; kh++)                         \
      A[m][kh] = *(const bf16x8*)(whT + (size_t)(w * 32 + m * 16 + lr) * NN + (S) * 64 + kh * 32 + q * 8); \
  }
#define PSTEP(S, AR, WB)                                                     \
  {                                                                          \
    f32x4 dv = *(const f32x4*)&dst_lds[(S) * 64 + j4];                       \
    float p0, p1, p2, p3;                                                    \
    { float x = srcv + dv[0]; x = fmaxf(x, 0.2f * x); p0 = AR[0] * __expf(x); } \
    { float x = srcv + dv[1]; x = fmaxf(x, 0.2f * x); p1 = AR[1] * __expf(x); } \
    { float x = srcv + dv[2]; x = fmaxf(x, 0.2f * x); p2 = AR[2] * __expf(x); } \
    { float x = srcv + dv[3]; x = fmaxf(x, 0.2f * x); p3 = AR[3] * __expf(x); } \
    lsum += (p0 + p1) + (p2 + p3);                                           \
    ushort4 st;                                                              \
    st.x = f2bf(p0); st.y = f2bf(p1); st.z = f2bf(p2); st.w = f2bf(p3);      \
    *(ushort4*)&pbuf[WB][pwoff] = st;                                        \
  }
#define CMP(RB, A)                                                           \
  {                                                                          \
    _Pragma("unroll") for (int kh = 0; kh < 2; kh++)                         \
    _Pragma("unroll") for (int n = 0; n < 2; n++) {                          \
      bf16x8 pf = *(const bf16x8*)&pbuf[RB][(kh * 2 + n) * 512 + (q * 16 + lr) * 8]; \
      _Pragma("unroll") for (int m = 0; m < 2; m++)                          \
        acc[m][n] = __builtin_amdgcn_mfma_f32_16x16x32_bf16(A[m][kh], pf, acc[m][n], 0, 0, 0); \
    }                                                                        \
  }

  // prologue
  RLOAD(0, R0);
  RLOAD(1, R1);
  ALOAD(0, A0);
  PSTEP(0, R0, 0);
  LBAR;

  int rb = 0, wb = 1;
  for (int t = 0; t < 128; t += 2) {
    // even step t: compute step t, stage P(t+1)
    if (t + 2 < 128) { RLOAD(t + 2, R0); }
    PSTEP(t + 1, R1, wb);
    ALOAD(t + 1, A1);
    CMP(rb, A0);
    LBAR;
    rb = wb; wb = (wb == 2) ? 0 : wb + 1;
    // odd step t+1: compute step t+1, stage P(t+2)
    if (t + 3 < 128) { RLOAD(t + 3, R1); }
    if (t + 2 < 128) {
      PSTEP(t + 2, R0, wb);
      ALOAD(t + 2, A0);
    }
    CMP(rb, A1);
    LBAR;
    rb = wb; wb = (wb == 2) ? 0 : wb + 1;
  }
#undef LBAR
#undef RLOAD
#undef ALOAD
#undef PSTEP
#undef CMP

  // l row-sums: 16 threads per row
  lsum += __shfl_xor(lsum, 1);
  lsum += __shfl_xor(lsum, 2);
  lsum += __shfl_xor(lsum, 4);
  lsum += __shfl_xor(lsum, 8);
  if ((tid & 15) == 0) l_lds[pi] = lsum;
  __syncthreads();

  // stage normalized h' tile (transpose) into dst_lds region, then coalesced store
  u16* ost = (u16*)dst_lds;  // [32][264] u16
#pragma unroll
  for (int n = 0; n < 2; n++) {
    float inv = 1.0f / l_lds[n * 16 + lr];
#pragma unroll
    for (int m = 0; m < 2; m++) {
      ushort4 st;
      st.x = f2bf(acc[m][n][0] * inv);
      st.y = f2bf(acc[m][n][1] * inv);
      st.z = f2bf(acc[m][n][2] * inv);
      st.w = f2bf(acc[m][n][3] * inv);
      *(ushort4*)&ost[(n * 16 + lr) * 264 + w * 32 + m * 16 + q * 4] = st;
    }
  }
  __syncthreads();
  {
    int r = tid >> 4;
    int c = (tid & 15) * 16;
    bf16x8 v0 = *(const bf16x8*)&ost[r * 264 + c];
    bf16x8 v1 = *(const bf16x8*)&ost[r * 264 + c + 8];
    *(bf16x8*)(hpb + (size_t)(i0 + r) * FD + c) = v0;
    *(bf16x8*)(hpb + (size_t)(i0 + r) * FD + c + 8) = v1;
  }
}

// ---- K4: fused GRUCell ----
__global__ __launch_bounds__(256) void k_gru(const u16* __restrict__ hpb,
                                             const u16* __restrict__ hb,
                                             const u16* __restrict__ wihb,
                                             const u16* __restrict__ whhb,
                                             const float* __restrict__ bih,
                                             const float* __restrict__ bhh,
                                             const float* __restrict__ h,
                                             float* __restrict__ out) {
  int tid = threadIdx.x;
  int lane = tid & 63;
  int wv = tid >> 6;
  int i0 = blockIdx.x * 32;
  int lr = lane & 15;
  int q = lane >> 4;
  int c = blockIdx.y * 64 + wv * 16 + lr;
  f32x4 gi[3][2] = {};
  f32x4 gh[3][2] = {};
  for (int kk = 0; kk < FD; kk += 32) {
    int kb = kk + q * 8;
    bf16x8 ap[2], ah[2], bi[3], bh[3];
#pragma unroll
    for (int m = 0; m < 2; m++) {
      ap[m] = *(const bf16x8*)(hpb + (size_t)(i0 + m * 16 + lr) * FD + kb);
      ah[m] = *(const bf16x8*)(hb + (size_t)(i0 + m * 16 + lr) * FD + kb);
    }
#pragma unroll
    for (int g = 0; g < 3; g++) {
      bi[g] = *(const bf16x8*)(wihb + (size_t)(g * 256 + c) * FD + kb);
      bh[g] = *(const bf16x8*)(whhb + (size_t)(g * 256 + c) * FD + kb);
    }
#pragma unroll
    for (int g = 0; g < 3; g++)
#pragma unroll
      for (int m = 0; m < 2; m++) {
        gi[g][m] = __builtin_amdgcn_mfma_f32_16x16x32_bf16(ap[m], bi[g], gi[g][m], 0, 0, 0);
        gh[g][m] = __builtin_amdgcn_mfma_f32_16x16x32_bf16(ah[m], bh[g], gh[g][m], 0, 0, 0);
      }
  }
  float bir = bih[c], biz = bih[256 + c], bin = bih[512 + c];
  float bhr = bhh[c], bhz = bhh[256 + c], bhn = bhh[512 + c];
#pragma unroll
  for (int m = 0; m < 2; m++)
#pragma unroll
    for (int j = 0; j < 4; j++) {
      int row = i0 + m * 16 + q * 4 + j;
      float rv = gi[0][m][j] + bir + gh[0][m][j] + bhr;
      float zv = gi[1][m][j] + biz + gh[1][m][j] + bhz;
      float r = 1.f / (1.f + __expf(-rv));
      float z = 1.f / (1.f + __expf(-zv));
      float nx = gi[2][m][j] + bin + r * (gh[2][m][j] + bhn);
      float n = 1.f - 2.f / (__expf(2.f * nx) + 1.f);
      float hv = h[(size_t)row * FD + c];
      out[(size_t)row * FD + c] = (1.f - z) * n + z * hv;
    }
}

extern "C" void kernel_launch(void* const* d_in, const int* in_sizes, int n_in,
                              void* d_out, int out_size, void* d_ws, size_t ws_size,
                              hipStream_t stream) {
  const float* h   = (const float*)d_in[0];
  const float* adj = (const float*)d_in[1];
  const float* W   = (const float*)d_in[2];
  const float* a   = (const float*)d_in[3];
  const float* wih = (const float*)d_in[4];
  const float* whh = (const float*)d_in[5];
  const float* bih = (const float*)d_in[6];
  const float* bhh = (const float*)d_in[7];
  float* out = (float*)d_out;

  char* ws = (char*)d_ws;
  u16* whT  = (u16*)(ws);                 // 4 MB   Wh transposed (bf16)
  u16* hpb  = (u16*)(ws + 4194304);       // 4 MB   h_prime (bf16)
  u16* hb   = (u16*)(ws + 8388608);       // 4 MB   h (bf16)
  u16* wihb = (u16*)(ws + 12582912);      // 384 KB
  u16* whhb = (u16*)(ws + 12976128);      // 384 KB
  float* srcv = (float*)(ws + 13369344);  // 32 KB
  float* dstv = (float*)(ws + 13402112);  // 32 KB

  hipMemsetAsync(ws + 13369344, 0, 65536, stream);
  k_wh<<<dim3(128, 4), 256, 0, stream>>>(h, W, a, whT, srcv, dstv);
  k_cast<<<2432, 256, 0, stream>>>(h, wih, whh, hb, wihb, whhb);
  k_att<<<256, 512, 0, stream>>>(adj, whT, srcv, dstv, hpb);
  k_gru<<<dim3(256, 4), 256, 0, stream>>>(hpb, hb, wihb, whhb, bih, bhh, h, out);
}

// Round 5
// 209.072 us; speedup vs baseline: 1.6865x; 1.1287x over previous
//
#include <hip/hip_runtime.h>

typedef __attribute__((ext_vector_type(8))) short bf16x8;
typedef __attribute__((ext_vector_type(4))) float f32x4;
typedef unsigned short u16;

#define NN 8192
#define FD 256

__device__ __forceinline__ u16 f2bf(float f) {
  union { float f; unsigned u; } v; v.f = f;
  unsigned r = v.u + 0x7FFF + ((v.u >> 16) & 1);
  return (u16)(r >> 16);
}

// load 8 consecutive f32 and round to a bf16x8 fragment
__device__ __forceinline__ bf16x8 ldcvt8(const float* __restrict__ p) {
  f32x4 x0 = *(const f32x4*)p;
  f32x4 x1 = *(const f32x4*)(p + 4);
  bf16x8 t;
  t[0] = (short)f2bf(x0[0]); t[1] = (short)f2bf(x0[1]);
  t[2] = (short)f2bf(x0[2]); t[3] = (short)f2bf(x0[3]);
  t[4] = (short)f2bf(x1[0]); t[5] = (short)f2bf(x1[1]);
  t[6] = (short)f2bf(x1[2]); t[7] = (short)f2bf(x1[3]);
  return t;
}

// ---- K1: Wh = h @ W -> whT[c][r] (bf16), fused src/dst partial dot + atomicAdd ----
__global__ __launch_bounds__(256) void k_wh(const float* __restrict__ h,
                                            const float* __restrict__ W,
                                            const float* __restrict__ a,
                                            u16* __restrict__ whT,
                                            float* __restrict__ src,
                                            float* __restrict__ dst) {
  int tid = threadIdx.x;
  int lane = tid & 63;
  int wv = tid >> 6;
  int r0 = blockIdx.x * 64 + (wv >> 1) * 32;
  int c0 = blockIdx.y * 64 + (wv & 1) * 32;
  int lr = lane & 15;
  int q = lane >> 4;

  f32x4 acc[2][2] = {};
  for (int kk = 0; kk < FD; kk += 32) {
    int kb = kk + q * 8;
    bf16x8 av[2], bv[2];
#pragma unroll
    for (int m = 0; m < 2; m++)
      av[m] = ldcvt8(h + (size_t)(r0 + m * 16 + lr) * FD + kb);
#pragma unroll
    for (int n = 0; n < 2; n++) {
      int col = c0 + n * 16 + lr;
      const float* p = W + (size_t)kb * FD + col;
      bf16x8 t;
#pragma unroll
      for (int e = 0; e < 8; e++) t[e] = (short)f2bf(p[(size_t)e * FD]);
      bv[n] = t;
    }
#pragma unroll
    for (int m = 0; m < 2; m++)
#pragma unroll
      for (int n = 0; n < 2; n++)
        acc[m][n] = __builtin_amdgcn_mfma_f32_16x16x32_bf16(av[m], bv[n], acc[m][n], 0, 0, 0);
  }
#pragma unroll
  for (int m = 0; m < 2; m++)
#pragma unroll
    for (int n = 0; n < 2; n++) {
      int gc = c0 + n * 16 + lr;
      int gr = r0 + m * 16 + q * 4;
      ushort4 st;
      st.x = f2bf(acc[m][n][0]);
      st.y = f2bf(acc[m][n][1]);
      st.z = f2bf(acc[m][n][2]);
      st.w = f2bf(acc[m][n][3]);
      *(ushort4*)(whT + (size_t)gc * NN + gr) = st;
    }
  float aA0 = a[c0 + lr], aA1 = a[c0 + 16 + lr];
  float aB0 = a[256 + c0 + lr], aB1 = a[256 + c0 + 16 + lr];
#pragma unroll
  for (int m = 0; m < 2; m++)
#pragma unroll
    for (int j = 0; j < 4; j++) {
      float s1 = acc[m][0][j] * aA0 + acc[m][1][j] * aA1;
      float s2 = acc[m][0][j] * aB0 + acc[m][1][j] * aB1;
#pragma unroll
      for (int sh = 1; sh < 16; sh <<= 1) {
        s1 += __shfl_xor(s1, sh);
        s2 += __shfl_xor(s2, sh);
      }
      if (lr == 0) {
        int row = r0 + m * 16 + q * 4 + j;
        atomicAdd(&src[row], s1);
        atomicAdd(&dst[row], s2);
      }
    }
}

// ---- K2: attention, BM=128 rows/block, JS=4 j-quarters, atomic f32 combine ----
// 256 blocks x 512 thr. jh = bid&3: with round-robin dispatch XCD = bid%8, each
// XCD sees exactly one jh -> its 1 MB whT j-slice stays L2-resident. 32 steps
// of 64 j. P in LDS [128][64] bf16 XOR-swizzled, triple-buffered; lgkm-only
// barrier keeps the adj/whT vmcnt prefetch queue alive across steps.
__global__ __launch_bounds__(512, 1) void k_att(const float* __restrict__ adj,
                                                const u16* __restrict__ whT,
                                                const float* __restrict__ src,
                                                const float* __restrict__ dst,
                                                float* __restrict__ hp,
                                                float* __restrict__ lg) {
  __shared__ u16 pbuf[3][8192];     // 3 x 16 KB
  __shared__ float dst_lds[2048];   // 8 KB
  __shared__ float lred[4][128];

  const int tid = threadIdx.x;
  const int lane = tid & 63;
  const int w = tid >> 6;
  const int lr = lane & 15;
  const int q = lane >> 4;
  const int bid = blockIdx.x;
  const int jh = bid & 3;
  const int i0 = (bid >> 2) * 128;
  const int jb = jh * 2048;

  const int pi = tid & 127;         // P row
  const int jg = tid >> 7;          // which 16-j group
  const float* adjP = adj + (size_t)(i0 + pi) * NN + jb + jg * 16;
  const float srcv = src[i0 + pi];
  const int c0 = w * 32;
  const u16* wp = whT + (size_t)(c0 + lr) * NN + jb + q * 8;
  const int pw0 = (pi * 64 + jg * 16) ^ ((pi & 7) << 3);
  const int pw1 = (pi * 64 + jg * 16 + 8) ^ ((pi & 7) << 3);

  f32x4 ar0[4], ar1[4];
  bf16x8 B0[2][2], B1[2][2];
  f32x4 acc[8][2] = {};
  float lsum = 0.f;

  *(f32x4*)&dst_lds[tid * 4] = *(const f32x4*)(dst + jb + tid * 4);

#define AL(S, AR)                                                              \
  { _Pragma("unroll") for (int v = 0; v < 4; v++)                              \
      AR[v] = *(const f32x4*)(adjP + (size_t)(S) * 64 + v * 4); }
#define BL(S, B)                                                               \
  { _Pragma("unroll") for (int kh = 0; kh < 2; kh++)                           \
    _Pragma("unroll") for (int n = 0; n < 2; n++)                              \
      B[kh][n] = *(const bf16x8*)(wp + (size_t)n * 16 * NN + (S) * 64 + kh * 32); }
#define PS(S, AR, WB)                                                          \
  {                                                                            \
    u16 pv[16];                                                                \
    _Pragma("unroll") for (int v = 0; v < 4; v++)                              \
      _Pragma("unroll") for (int e = 0; e < 4; e++) {                          \
        float x = srcv + dst_lds[(S) * 64 + jg * 16 + v * 4 + e];              \
        x = fmaxf(x, 0.2f * x);                                                \
        float p = AR[v][e] * __expf(x);                                        \
        lsum += p;                                                             \
        pv[v * 4 + e] = f2bf(p);                                               \
      }                                                                        \
    bf16x8 s0, s1;                                                             \
    _Pragma("unroll") for (int e = 0; e < 8; e++) {                            \
      s0[e] = (short)pv[e]; s1[e] = (short)pv[8 + e];                          \
    }                                                                          \
    *(bf16x8*)&pbuf[WB][pw0] = s0;                                             \
    *(bf16x8*)&pbuf[WB][pw1] = s1;                                             \
  }
#define CMPS(RB, B)                                                            \
  {                                                                            \
    _Pragma("unroll") for (int m = 0; m < 8; m++)                              \
      _Pragma("unroll") for (int kh = 0; kh < 2; kh++) {                       \
        bf16x8 pf = *(const bf16x8*)&pbuf[RB][((m * 16 + lr) * 64 + kh * 32 + q * 8) ^ ((lr & 7) << 3)]; \
        acc[m][0] = __builtin_amdgcn_mfma_f32_16x16x32_bf16(pf, B[kh][0], acc[m][0], 0, 0, 0); \
        acc[m][1] = __builtin_amdgcn_mfma_f32_16x16x32_bf16(pf, B[kh][1], acc[m][1], 0, 0, 0); \
      }                                                                        \
  }
#define LBAR asm volatile("s_waitcnt lgkmcnt(0)\n\ts_barrier" ::: "memory")

  AL(0, ar0);
  AL(1, ar1);
  BL(0, B0);
  __syncthreads();   // dst_lds ready
  PS(0, ar0, 0);
  LBAR;

  int rb = 0, wb = 1;
  for (int t = 0; t < 32; t += 2) {
    if (t + 2 < 32) AL(t + 2, ar0);
    PS(t + 1, ar1, wb);
    BL(t + 1, B1);
    CMPS(rb, B0);
    LBAR;
    rb = wb; wb = (wb == 2) ? 0 : wb + 1;
    if (t + 3 < 32) AL(t + 3, ar1);
    if (t + 2 < 32) {
      PS(t + 2, ar0, wb);
      BL(t + 2, B0);
    }
    CMPS(rb, B1);
    LBAR;
    rb = wb; wb = (wb == 2) ? 0 : wb + 1;
  }
#undef AL
#undef BL
#undef PS
#undef CMPS
#undef LBAR

  lred[jg][pi] = lsum;
  __syncthreads();
  if (tid < 128) {
    float l = (lred[0][tid] + lred[1][tid]) + (lred[2][tid] + lred[3][tid]);
    atomicAdd(&lg[i0 + tid], l);
  }
#pragma unroll
  for (int m = 0; m < 8; m++)
#pragma unroll
    for (int n = 0; n < 2; n++)
#pragma unroll
      for (int j = 0; j < 4; j++)
        atomicAdd(&hp[(size_t)(i0 + m * 16 + q * 4 + j) * FD + c0 + n * 16 + lr],
                  acc[m][n][j]);
}

// ---- K3: normalize hp by row-sum, cast to bf16 (hpb aliases whT region) ----
__global__ __launch_bounds__(256) void k_norm(const float* __restrict__ hp,
                                              const float* __restrict__ lg,
                                              u16* __restrict__ hpb) {
  int g = blockIdx.x * 1024 + threadIdx.x * 4;
  f32x4 v = *(const f32x4*)(hp + g);
  float inv = 1.0f / lg[g >> 8];
  ushort4 st;
  st.x = f2bf(v[0] * inv);
  st.y = f2bf(v[1] * inv);
  st.z = f2bf(v[2] * inv);
  st.w = f2bf(v[3] * inv);
  *(ushort4*)(hpb + g) = st;
}

// ---- K4: fused GRUCell (h, w_ih, w_hh cast f32->bf16 inline) ----
__global__ __launch_bounds__(256) void k_gru(const u16* __restrict__ hpb,
                                             const float* __restrict__ h,
                                             const float* __restrict__ wih,
                                             const float* __restrict__ whh,
                                             const float* __restrict__ bih,
                                             const float* __restrict__ bhh,
                                             float* __restrict__ out) {
  int tid = threadIdx.x;
  int lane = tid & 63;
  int wv = tid >> 6;
  int i0 = blockIdx.x * 32;
  int lr = lane & 15;
  int q = lane >> 4;
  int c = blockIdx.y * 64 + wv * 16 + lr;
  f32x4 gi[3][2] = {};
  f32x4 gh[3][2] = {};
  for (int kk = 0; kk < FD; kk += 32) {
    int kb = kk + q * 8;
    bf16x8 ap[2], ah[2], bi[3], bh[3];
#pragma unroll
    for (int m = 0; m < 2; m++) {
      ap[m] = *(const bf16x8*)(hpb + (size_t)(i0 + m * 16 + lr) * FD + kb);
      ah[m] = ldcvt8(h + (size_t)(i0 + m * 16 + lr) * FD + kb);
    }
#pragma unroll
    for (int g = 0; g < 3; g++) {
      bi[g] = ldcvt8(wih + (size_t)(g * 256 + c) * FD + kb);
      bh[g] = ldcvt8(whh + (size_t)(g * 256 + c) * FD + kb);
    }
#pragma unroll
    for (int g = 0; g < 3; g++)
#pragma unroll
      for (int m = 0; m < 2; m++) {
        gi[g][m] = __builtin_amdgcn_mfma_f32_16x16x32_bf16(ap[m], bi[g], gi[g][m], 0, 0, 0);
        gh[g][m] = __builtin_amdgcn_mfma_f32_16x16x32_bf16(ah[m], bh[g], gh[g][m], 0, 0, 0);
      }
  }
  float bir = bih[c], biz = bih[256 + c], bin = bih[512 + c];
  float bhr = bhh[c], bhz = bhh[256 + c], bhn = bhh[512 + c];
#pragma unroll
  for (int m = 0; m < 2; m++)
#pragma unroll
    for (int j = 0; j < 4; j++) {
      int row = i0 + m * 16 + q * 4 + j;
      float rv = gi[0][m][j] + bir + gh[0][m][j] + bhr;
      float zv = gi[1][m][j] + biz + gh[1][m][j] + bhz;
      float r = 1.f / (1.f + __expf(-rv));
      float z = 1.f / (1.f + __expf(-zv));
      float nx = gi[2][m][j] + bin + r * (gh[2][m][j] + bhn);
      float n = 1.f - 2.f / (__expf(2.f * nx) + 1.f);
      float hv = h[(size_t)row * FD + c];
      out[(size_t)row * FD + c] = (1.f - z) * n + z * hv;
    }
}

extern "C" void kernel_launch(void* const* d_in, const int* in_sizes, int n_in,
                              void* d_out, int out_size, void* d_ws, size_t ws_size,
                              hipStream_t stream) {
  const float* h   = (const float*)d_in[0];
  const float* adj = (const float*)d_in[1];
  const float* W   = (const float*)d_in[2];
  const float* a   = (const float*)d_in[3];
  const float* wih = (const float*)d_in[4];
  const float* whh = (const float*)d_in[5];
  const float* bih = (const float*)d_in[6];
  const float* bhh = (const float*)d_in[7];
  float* out = (float*)d_out;

  // Workspace layout (12.68 MB total — within the proven-safe R1-R3 footprint):
  char* ws = (char*)d_ws;
  u16* whT   = (u16*)(ws);                  // [0, 4 MB)   Wh^T bf16; reused as hpb after k_att
  u16* hpb   = (u16*)(ws);                  //   alias — written by k_norm, read by k_gru
  float* hp  = (float*)(ws + 4194304);      // [4 MB, 12 MB) h' f32 accumulators
  float* lg  = (float*)(ws + 12582912);     // 32 KB row sums
  float* srcv = (float*)(ws + 12615680);    // 32 KB
  float* dstv = (float*)(ws + 12648448);    // 32 KB  -> end 12681216
  (void)ws_size;

  hipMemsetAsync(ws + 4194304, 0, 8486912, stream);  // hp + lg + src + dst
  k_wh<<<dim3(128, 4), 256, 0, stream>>>(h, W, a, whT, srcv, dstv);
  k_att<<<256, 512, 0, stream>>>(adj, whT, srcv, dstv, hp, lg);
  k_norm<<<2048, 256, 0, stream>>>(hp, lg, hpb);
  k_gru<<<dim3(256, 4), 256, 0, stream>>>(hpb, h, wih, whh, bih, bhh, out);
}